// Round 4
// baseline (67.291 us; speedup 1.0000x reference)
//
#include <hip/hip_runtime.h>

#define GAMMA   0.99f
#define EPSILON 1e-8f
#define CLIPR   10.0f
#define VAR_MOM 0.99f

constexpr int T = 4096;
constexpr int B = 4096;
constexpr int GSEG = 16;   // segments per column for two-level carry pass

// ---------------------------------------------------------------------------
// K1: per (chunk c, column pair g) compute carry-independent chunk summaries.
// ret[t] = v_t + p_t * carry_in.
// Batched register staging: issue ALL loads of the next NB-step batch, then
// sched_barrier(0) so the compiler cannot sink them, then math on the current
// batch. ~2*NB dwordx2 loads (16KB/wave) stay in flight -> BW-bound, not
// latency-bound.
// ---------------------------------------------------------------------------
template <int L, int NB>
__global__ __launch_bounds__(256) void chunk_scan_k(
    const float2* __restrict__ rewards,
    const float2* __restrict__ dones,
    float* __restrict__ arrs,   // 7 arrays, stride S=C*B
    int C) {
    const int g = blockIdx.x * blockDim.x + threadIdx.x;  // [0, B/2)
    const int c = blockIdx.y;
    constexpr int W = B / 2;
    const size_t base = (size_t)c * L * W + g;
    const float2* __restrict__ rp = rewards + base;
    const float2* __restrict__ dp = dones   + base;

    // step j (j=0..L-1) processes t = t0 + L-1-j  -> element offset (L-1-j)*W
    float2 rA[NB], dA[NB], rB[NB], dB[NB];

#pragma unroll
    for (int j = 0; j < NB; ++j) {
        rA[j] = rp[(size_t)(L - 1 - j) * W];
        dA[j] = dp[(size_t)(L - 1 - j) * W];
    }
    __builtin_amdgcn_sched_barrier(0);

    float v0 = 0.f, p0 = 1.f, sv0 = 0.f, sp0 = 0.f, sv20 = 0.f, svp0 = 0.f, sp20 = 0.f;
    float v1 = 0.f, p1 = 1.f, sv1 = 0.f, sp1 = 0.f, sv21 = 0.f, svp1 = 0.f, sp21 = 0.f;

#define STEP(rv, dv)                                                      \
    do {                                                                  \
        const float a0 = GAMMA - GAMMA * (dv).x;                          \
        const float a1 = GAMMA - GAMMA * (dv).y;                          \
        v0 = fmaf(a0, v0, (rv).x);  p0 *= a0;                             \
        v1 = fmaf(a1, v1, (rv).y);  p1 *= a1;                             \
        sv0 += v0;  sp0 += p0;                                            \
        sv20 = fmaf(v0, v0, sv20);  svp0 = fmaf(v0, p0, svp0);            \
        sp20 = fmaf(p0, p0, sp20);                                        \
        sv1 += v1;  sp1 += p1;                                            \
        sv21 = fmaf(v1, v1, sv21);  svp1 = fmaf(v1, p1, svp1);            \
        sp21 = fmaf(p1, p1, sp21);                                        \
    } while (0)

    constexpr int NBATCH = L / NB;   // even by construction
#pragma unroll
    for (int bb = 0; bb < NBATCH; bb += 2) {
        // ---- batch bb lives in A; prefetch batch bb+1 into B ----
        if (bb + 1 < NBATCH) {
#pragma unroll
            for (int j = 0; j < NB; ++j) {
                const int s = (bb + 1) * NB + j;
                rB[j] = rp[(size_t)(L - 1 - s) * W];
                dB[j] = dp[(size_t)(L - 1 - s) * W];
            }
        }
        __builtin_amdgcn_sched_barrier(0);
#pragma unroll
        for (int j = 0; j < NB; ++j) STEP(rA[j], dA[j]);
        __builtin_amdgcn_sched_barrier(0);

        // ---- batch bb+1 lives in B; prefetch batch bb+2 into A ----
        if (bb + 1 < NBATCH) {
            if (bb + 2 < NBATCH) {
#pragma unroll
                for (int j = 0; j < NB; ++j) {
                    const int s = (bb + 2) * NB + j;
                    rA[j] = rp[(size_t)(L - 1 - s) * W];
                    dA[j] = dp[(size_t)(L - 1 - s) * W];
                }
            }
            __builtin_amdgcn_sched_barrier(0);
#pragma unroll
            for (int j = 0; j < NB; ++j) STEP(rB[j], dB[j]);
            __builtin_amdgcn_sched_barrier(0);
        }
    }
#undef STEP

    const size_t S   = (size_t)C * B;
    const size_t idx = (size_t)c * B + 2 * g;
    *(float2*)&arrs[0 * S + idx] = make_float2(v0,  v1);    // v_first
    *(float2*)&arrs[1 * S + idx] = make_float2(p0,  p1);    // p_tot
    *(float2*)&arrs[2 * S + idx] = make_float2(sv0, sv1);
    *(float2*)&arrs[3 * S + idx] = make_float2(sp0, sp1);
    *(float2*)&arrs[4 * S + idx] = make_float2(sv20, sv21);
    *(float2*)&arrs[5 * S + idx] = make_float2(svp0, svp1);
    *(float2*)&arrs[6 * S + idx] = make_float2(sp20, sp21);
}

// ---------------------------------------------------------------------------
// K2a: compose chunk summaries within each of GSEG segments per column.
// ---------------------------------------------------------------------------
__global__ void seg_compose(const float* __restrict__ arrs, int C,
                            float* __restrict__ seg) {
    const int tid = blockIdx.x * blockDim.x + threadIdx.x;
    const int b = tid & (B - 1);
    const int s = tid >> 12;           // / B
    const int Cs = C / GSEG;
    const size_t S = (size_t)C * B;

    float V = 0.f, P = 1.f, SV = 0.f, SP = 0.f, SV2 = 0.f, SVP = 0.f, SP2 = 0.f;
    for (int c = (s + 1) * Cs - 1; c >= s * Cs; --c) {
        const size_t idx = (size_t)c * B + b;
        const float vf  = arrs[0 * S + idx];
        const float pt  = arrs[1 * S + idx];
        const float sv  = arrs[2 * S + idx];
        const float sp  = arrs[3 * S + idx];
        const float sv2 = arrs[4 * S + idx];
        const float svp = arrs[5 * S + idx];
        const float sp2 = arrs[6 * S + idx];
        SV2 += sv2 + 2.f * svp * V + sp2 * V * V;
        SVP += svp * P + sp2 * V * P;
        SP2 += sp2 * P * P;
        SV  += sv + sp * V;
        SP  += sp * P;
        V = fmaf(pt, V, vf);
        P *= pt;
    }
    const size_t SG = (size_t)GSEG * B;
    const size_t o  = (size_t)s * B + b;
    seg[0 * SG + o] = V;   seg[1 * SG + o] = P;
    seg[2 * SG + o] = SV;  seg[3 * SG + o] = SP;
    seg[4 * SG + o] = SV2; seg[5 * SG + o] = SVP; seg[6 * SG + o] = SP2;
}

// K2b: finish carry across GSEG segments per column; exact sums in double.
__global__ void carry_final(const float* __restrict__ seg,
                            const float* __restrict__ return_init,
                            double* __restrict__ acc) {
    const int b = blockIdx.x * blockDim.x + threadIdx.x;
    const size_t SG = (size_t)GSEG * B;
    double s = 0.0, s2 = 0.0;
    float carry = return_init[0];
    for (int g = GSEG - 1; g >= 0; --g) {
        const size_t o = (size_t)g * B + b;
        const float V   = seg[0 * SG + o];
        const float P   = seg[1 * SG + o];
        const float SV  = seg[2 * SG + o];
        const float SP  = seg[3 * SG + o];
        const float SV2 = seg[4 * SG + o];
        const float SVP = seg[5 * SG + o];
        const float SP2 = seg[6 * SG + o];
        const double cd = (double)carry;
        s  += (double)SV  + cd * (double)SP;
        s2 += (double)SV2 + 2.0 * cd * (double)SVP + cd * cd * (double)SP2;
        carry = fmaf(P, carry, V);
    }
    __shared__ double sh_s[256];
    __shared__ double sh_s2[256];
    const int tid = threadIdx.x;
    sh_s[tid] = s; sh_s2[tid] = s2;
    __syncthreads();
    for (int stride = 128; stride > 0; stride >>= 1) {
        if (tid < stride) {
            sh_s[tid]  += sh_s[tid + stride];
            sh_s2[tid] += sh_s2[tid + stride];
        }
        __syncthreads();
    }
    if (tid == 0) {
        atomicAdd(&acc[0], sh_s[0]);
        atomicAdd(&acc[1], sh_s2[0]);
    }
}

// K2 fallback (single-level) if ws too small for seg scratch.
__global__ void carry_reduce(const float* __restrict__ arrs, int C,
                             const float* __restrict__ return_init,
                             double* __restrict__ acc) {
    const int b = blockIdx.x * blockDim.x + threadIdx.x;
    const size_t S = (size_t)C * B;
    double s = 0.0, s2 = 0.0;
    float carry = return_init[0];
#pragma unroll 4
    for (int c = C - 1; c >= 0; --c) {
        const size_t idx = (size_t)c * B + b;
        const float vf  = arrs[0 * S + idx];
        const float pt  = arrs[1 * S + idx];
        const float sv  = arrs[2 * S + idx];
        const float sp  = arrs[3 * S + idx];
        const float sv2 = arrs[4 * S + idx];
        const float svp = arrs[5 * S + idx];
        const float sp2 = arrs[6 * S + idx];
        const double cd = (double)carry;
        s  += (double)sv  + cd * (double)sp;
        s2 += (double)sv2 + 2.0 * cd * (double)svp + cd * cd * (double)sp2;
        carry = fmaf(pt, carry, vf);
    }
    __shared__ double sh_s[256];
    __shared__ double sh_s2[256];
    const int tid = threadIdx.x;
    sh_s[tid] = s; sh_s2[tid] = s2;
    __syncthreads();
    for (int stride = 128; stride > 0; stride >>= 1) {
        if (tid < stride) {
            sh_s[tid]  += sh_s[tid + stride];
            sh_s2[tid] += sh_s2[tid + stride];
        }
        __syncthreads();
    }
    if (tid == 0) {
        atomicAdd(&acc[0], sh_s[0]);
        atomicAdd(&acc[1], sh_s2[0]);
    }
}

// K3: scale = 1/sqrt(var_new + eps); out = clip(rewards * scale).
__global__ void normalize(const float* __restrict__ rewards,
                          float* __restrict__ out,
                          const double* __restrict__ acc,
                          const float* __restrict__ var_init,
                          int n4) {
    const double s  = acc[0];
    const double s2 = acc[1];
    const double n  = (double)T * (double)B;
    const double ret_var = (s2 - s * s / n) / (n - 1.0);   // ddof=1
    const float var_new = (float)((double)var_init[0] * (double)VAR_MOM +
                                  ret_var * (1.0 - (double)VAR_MOM));
    const float scale = 1.0f / sqrtf(var_new + EPSILON);

    const float4* __restrict__ r4 = (const float4*)rewards;
    float4* __restrict__ o4 = (float4*)out;
    const int stride = gridDim.x * blockDim.x;
    for (int i = blockIdx.x * blockDim.x + threadIdx.x; i < n4; i += stride) {
        float4 x = r4[i];
        float4 y;
        y.x = fminf(fmaxf(x.x * scale, -CLIPR), CLIPR);
        y.y = fminf(fmaxf(x.y * scale, -CLIPR), CLIPR);
        y.z = fminf(fmaxf(x.z * scale, -CLIPR), CLIPR);
        y.w = fminf(fmaxf(x.w * scale, -CLIPR), CLIPR);
        o4[i] = y;
    }
}

extern "C" void kernel_launch(void* const* d_in, const int* in_sizes, int n_in,
                              void* d_out, int out_size, void* d_ws, size_t ws_size,
                              hipStream_t stream) {
    const float* rewards     = (const float*)d_in[0];
    const float* dones       = (const float*)d_in[1];
    const float* return_init = (const float*)d_in[2];
    const float* var_init    = (const float*)d_in[3];
    float* out = (float*)d_out;

    double* acc  = (double*)d_ws;
    float*  arrs = (float*)((char*)d_ws + 64);

    hipMemsetAsync(d_ws, 0, 16, stream);   // zero the two f64 accumulators

    const size_t arrs128 = (size_t)7 * 128 * B * 4;
    const size_t arrs64  = (size_t)7 * 64  * B * 4;
    const size_t segsz   = (size_t)7 * GSEG * B * 4;

    const float2* r2 = (const float2*)rewards;
    const float2* d2 = (const float2*)dones;

    int C;
    float* segp = nullptr;
    if (ws_size >= 64 + arrs128 + segsz) {
        C = 128;  segp = (float*)((char*)d_ws + 64 + arrs128);
        dim3 g1((B / 2) / 256, C);
        chunk_scan_k<32, 8><<<g1, 256, 0, stream>>>(r2, d2, arrs, C);
    } else if (ws_size >= 64 + arrs128) {
        C = 128;
        dim3 g1((B / 2) / 256, C);
        chunk_scan_k<32, 8><<<g1, 256, 0, stream>>>(r2, d2, arrs, C);
    } else {
        C = 64;
        if (ws_size >= 64 + arrs64 + segsz) segp = (float*)((char*)d_ws + 64 + arrs64);
        dim3 g1((B / 2) / 256, C);
        chunk_scan_k<64, 8><<<g1, 256, 0, stream>>>(r2, d2, arrs, C);
    }

    if (segp) {
        seg_compose<<<(B * GSEG) / 256, 256, 0, stream>>>(arrs, C, segp);
        carry_final<<<B / 256, 256, 0, stream>>>(segp, return_init, acc);
    } else {
        carry_reduce<<<B / 256, 256, 0, stream>>>(arrs, C, return_init, acc);
    }

    const int n4 = (T * B) / 4;
    normalize<<<4096, 256, 0, stream>>>(rewards, out, acc, var_init, n4);
}

// Round 5
// 65.968 us; speedup vs baseline: 1.0201x; 1.0201x over previous
//
#include <hip/hip_runtime.h>

#define GAMMA   0.99f
#define EPSILON 1e-8f
#define CLIPR   10.0f
#define VAR_MOM 0.99f

constexpr int T = 4096;
constexpr int B = 4096;
constexpr int GSEG = 16;

// ---------------------------------------------------------------------------
// K1 (pipelined): per (chunk c, column pair g), L=32, C=128.
// Inline-asm global_load_dwordx2 + hand-counted s_waitcnt vmcnt(N), 8-pair
// deep pipeline. Volatile asm cannot be sunk; counted waits (16 in steady
// state) keep 16 loads in flight per wave. sched_barrier(0) after each wait
// stops register-only math from hoisting above it (guide rule 18).
// ---------------------------------------------------------------------------
__global__ __launch_bounds__(256) void chunk_scan_pipe(
    const float2* __restrict__ rewards,
    const float2* __restrict__ dones,
    float* __restrict__ arrs) {
    constexpr int L = 32;
    constexpr int C = 128;
    constexpr int W = B / 2;
    const int g = blockIdx.x * blockDim.x + threadIdx.x;  // [0, W)
    const int c = blockIdx.y;
    const float2* __restrict__ rp = rewards + (size_t)c * L * W + g;
    const float2* __restrict__ dp = dones   + (size_t)c * L * W + g;

    float2 rv[L], dv[L];

    float v0 = 0.f, p0 = 1.f, sv0 = 0.f, sp0 = 0.f, sv20 = 0.f, svp0 = 0.f, sp20 = 0.f;
    float v1 = 0.f, p1 = 1.f, sv1 = 0.f, sp1 = 0.f, sv21 = 0.f, svp1 = 0.f, sp21 = 0.f;

#define PISSUE(j)                                                             \
    {                                                                         \
        const float2* ra_ = rp + (size_t)(L - 1 - (j)) * W;                   \
        const float2* da_ = dp + (size_t)(L - 1 - (j)) * W;                   \
        asm volatile("global_load_dwordx2 %0, %1, off"                        \
                     : "=&v"(rv[j]) : "v"(ra_));                              \
        asm volatile("global_load_dwordx2 %0, %1, off"                        \
                     : "=&v"(dv[j]) : "v"(da_));                              \
    }

#define WAITN(n)                                                              \
    asm volatile("s_waitcnt vmcnt(" #n ")" ::: "memory");                     \
    __builtin_amdgcn_sched_barrier(0);

#define STEP(j)                                                               \
    {                                                                         \
        const float a0 = GAMMA - GAMMA * dv[j].x;                             \
        const float a1 = GAMMA - GAMMA * dv[j].y;                             \
        v0 = fmaf(a0, v0, rv[j].x);  p0 *= a0;                                \
        v1 = fmaf(a1, v1, rv[j].y);  p1 *= a1;                                \
        sv0 += v0;  sp0 += p0;                                                \
        sv20 = fmaf(v0, v0, sv20);  svp0 = fmaf(v0, p0, svp0);                \
        sp20 = fmaf(p0, p0, sp20);                                            \
        sv1 += v1;  sp1 += p1;                                                \
        sv21 = fmaf(v1, v1, sv21);  svp1 = fmaf(v1, p1, svp1);                \
        sp21 = fmaf(p1, p1, sp21);                                            \
    }

    // prologue: pairs 0..7 in flight (16 loads)
    PISSUE(0) PISSUE(1) PISSUE(2) PISSUE(3)
    PISSUE(4) PISSUE(5) PISSUE(6) PISSUE(7)

    // steady state: issue pair j+8, wait until pair j landed (16 outstanding)
#define BODY(j)  PISSUE((j) + 8) WAITN(16) STEP(j)
    BODY(0)  BODY(1)  BODY(2)  BODY(3)  BODY(4)  BODY(5)  BODY(6)  BODY(7)
    BODY(8)  BODY(9)  BODY(10) BODY(11) BODY(12) BODY(13) BODY(14) BODY(15)
    BODY(16) BODY(17) BODY(18) BODY(19) BODY(20) BODY(21) BODY(22) BODY(23)

    // drain tail
    WAITN(14) STEP(24)
    WAITN(12) STEP(25)
    WAITN(10) STEP(26)
    WAITN(8)  STEP(27)
    WAITN(6)  STEP(28)
    WAITN(4)  STEP(29)
    WAITN(2)  STEP(30)
    WAITN(0)  STEP(31)

#undef BODY
#undef STEP
#undef WAITN
#undef PISSUE

    const size_t S   = (size_t)C * B;
    const size_t idx = (size_t)c * B + 2 * g;
    *(float2*)&arrs[0 * S + idx] = make_float2(v0,  v1);
    *(float2*)&arrs[1 * S + idx] = make_float2(p0,  p1);
    *(float2*)&arrs[2 * S + idx] = make_float2(sv0, sv1);
    *(float2*)&arrs[3 * S + idx] = make_float2(sp0, sp1);
    *(float2*)&arrs[4 * S + idx] = make_float2(sv20, sv21);
    *(float2*)&arrs[5 * S + idx] = make_float2(svp0, svp1);
    *(float2*)&arrs[6 * S + idx] = make_float2(sp20, sp21);
}

// Fallback simple K1 (only if ws can't hold C=128 arrays).
template <int L>
__global__ __launch_bounds__(256) void chunk_scan_simple(
    const float2* __restrict__ rewards,
    const float2* __restrict__ dones,
    float* __restrict__ arrs, int C) {
    const int g = blockIdx.x * blockDim.x + threadIdx.x;
    const int c = blockIdx.y;
    constexpr int W = B / 2;
    const size_t base = (size_t)c * L * W + g;
    float v0 = 0.f, p0 = 1.f, sv0 = 0.f, sp0 = 0.f, sv20 = 0.f, svp0 = 0.f, sp20 = 0.f;
    float v1 = 0.f, p1 = 1.f, sv1 = 0.f, sp1 = 0.f, sv21 = 0.f, svp1 = 0.f, sp21 = 0.f;
    for (int j = 0; j < L; ++j) {
        const float2 rvv = rewards[base + (size_t)(L - 1 - j) * W];
        const float2 dvv = dones[base + (size_t)(L - 1 - j) * W];
        const float a0 = GAMMA - GAMMA * dvv.x;
        const float a1 = GAMMA - GAMMA * dvv.y;
        v0 = fmaf(a0, v0, rvv.x);  p0 *= a0;
        v1 = fmaf(a1, v1, rvv.y);  p1 *= a1;
        sv0 += v0;  sp0 += p0;
        sv20 = fmaf(v0, v0, sv20);  svp0 = fmaf(v0, p0, svp0);  sp20 = fmaf(p0, p0, sp20);
        sv1 += v1;  sp1 += p1;
        sv21 = fmaf(v1, v1, sv21);  svp1 = fmaf(v1, p1, svp1);  sp21 = fmaf(p1, p1, sp21);
    }
    const size_t S   = (size_t)C * B;
    const size_t idx = (size_t)c * B + 2 * g;
    *(float2*)&arrs[0 * S + idx] = make_float2(v0,  v1);
    *(float2*)&arrs[1 * S + idx] = make_float2(p0,  p1);
    *(float2*)&arrs[2 * S + idx] = make_float2(sv0, sv1);
    *(float2*)&arrs[3 * S + idx] = make_float2(sp0, sp1);
    *(float2*)&arrs[4 * S + idx] = make_float2(sv20, sv21);
    *(float2*)&arrs[5 * S + idx] = make_float2(svp0, svp1);
    *(float2*)&arrs[6 * S + idx] = make_float2(sp20, sp21);
}

// K2a: compose chunk summaries within each of GSEG segments per column.
__global__ void seg_compose(const float* __restrict__ arrs, int C,
                            float* __restrict__ seg) {
    const int tid = blockIdx.x * blockDim.x + threadIdx.x;
    const int b = tid & (B - 1);
    const int s = tid >> 12;
    const int Cs = C / GSEG;
    const size_t S = (size_t)C * B;
    float V = 0.f, P = 1.f, SV = 0.f, SP = 0.f, SV2 = 0.f, SVP = 0.f, SP2 = 0.f;
    for (int c = (s + 1) * Cs - 1; c >= s * Cs; --c) {
        const size_t idx = (size_t)c * B + b;
        const float vf  = arrs[0 * S + idx];
        const float pt  = arrs[1 * S + idx];
        const float sv  = arrs[2 * S + idx];
        const float sp  = arrs[3 * S + idx];
        const float sv2 = arrs[4 * S + idx];
        const float svp = arrs[5 * S + idx];
        const float sp2 = arrs[6 * S + idx];
        SV2 += sv2 + 2.f * svp * V + sp2 * V * V;
        SVP += svp * P + sp2 * V * P;
        SP2 += sp2 * P * P;
        SV  += sv + sp * V;
        SP  += sp * P;
        V = fmaf(pt, V, vf);
        P *= pt;
    }
    const size_t SG = (size_t)GSEG * B;
    const size_t o  = (size_t)s * B + b;
    seg[0 * SG + o] = V;   seg[1 * SG + o] = P;
    seg[2 * SG + o] = SV;  seg[3 * SG + o] = SP;
    seg[4 * SG + o] = SV2; seg[5 * SG + o] = SVP; seg[6 * SG + o] = SP2;
}

__global__ void carry_final(const float* __restrict__ seg,
                            const float* __restrict__ return_init,
                            double* __restrict__ acc) {
    const int b = blockIdx.x * blockDim.x + threadIdx.x;
    const size_t SG = (size_t)GSEG * B;
    double s = 0.0, s2 = 0.0;
    float carry = return_init[0];
    for (int g = GSEG - 1; g >= 0; --g) {
        const size_t o = (size_t)g * B + b;
        const float V   = seg[0 * SG + o];
        const float P   = seg[1 * SG + o];
        const float SV  = seg[2 * SG + o];
        const float SP  = seg[3 * SG + o];
        const float SV2 = seg[4 * SG + o];
        const float SVP = seg[5 * SG + o];
        const float SP2 = seg[6 * SG + o];
        const double cd = (double)carry;
        s  += (double)SV  + cd * (double)SP;
        s2 += (double)SV2 + 2.0 * cd * (double)SVP + cd * cd * (double)SP2;
        carry = fmaf(P, carry, V);
    }
    __shared__ double sh_s[256];
    __shared__ double sh_s2[256];
    const int tid = threadIdx.x;
    sh_s[tid] = s; sh_s2[tid] = s2;
    __syncthreads();
    for (int stride = 128; stride > 0; stride >>= 1) {
        if (tid < stride) {
            sh_s[tid]  += sh_s[tid + stride];
            sh_s2[tid] += sh_s2[tid + stride];
        }
        __syncthreads();
    }
    if (tid == 0) {
        atomicAdd(&acc[0], sh_s[0]);
        atomicAdd(&acc[1], sh_s2[0]);
    }
}

__global__ void carry_reduce(const float* __restrict__ arrs, int C,
                             const float* __restrict__ return_init,
                             double* __restrict__ acc) {
    const int b = blockIdx.x * blockDim.x + threadIdx.x;
    const size_t S = (size_t)C * B;
    double s = 0.0, s2 = 0.0;
    float carry = return_init[0];
#pragma unroll 4
    for (int c = C - 1; c >= 0; --c) {
        const size_t idx = (size_t)c * B + b;
        const float vf  = arrs[0 * S + idx];
        const float pt  = arrs[1 * S + idx];
        const float sv  = arrs[2 * S + idx];
        const float sp  = arrs[3 * S + idx];
        const float sv2 = arrs[4 * S + idx];
        const float svp = arrs[5 * S + idx];
        const float sp2 = arrs[6 * S + idx];
        const double cd = (double)carry;
        s  += (double)sv  + cd * (double)sp;
        s2 += (double)sv2 + 2.0 * cd * (double)svp + cd * cd * (double)sp2;
        carry = fmaf(pt, carry, vf);
    }
    __shared__ double sh_s[256];
    __shared__ double sh_s2[256];
    const int tid = threadIdx.x;
    sh_s[tid] = s; sh_s2[tid] = s2;
    __syncthreads();
    for (int stride = 128; stride > 0; stride >>= 1) {
        if (tid < stride) {
            sh_s[tid]  += sh_s[tid + stride];
            sh_s2[tid] += sh_s2[tid + stride];
        }
        __syncthreads();
    }
    if (tid == 0) {
        atomicAdd(&acc[0], sh_s[0]);
        atomicAdd(&acc[1], sh_s2[0]);
    }
}

// K3: scale = 1/sqrt(var_new + eps); out = clip(rewards * scale).
__global__ void normalize(const float* __restrict__ rewards,
                          float* __restrict__ out,
                          const double* __restrict__ acc,
                          const float* __restrict__ var_init,
                          int n4) {
    const double s  = acc[0];
    const double s2 = acc[1];
    const double n  = (double)T * (double)B;
    const double ret_var = (s2 - s * s / n) / (n - 1.0);
    const float var_new = (float)((double)var_init[0] * (double)VAR_MOM +
                                  ret_var * (1.0 - (double)VAR_MOM));
    const float scale = 1.0f / sqrtf(var_new + EPSILON);

    const float4* __restrict__ r4 = (const float4*)rewards;
    float4* __restrict__ o4 = (float4*)out;
    const int stride = gridDim.x * blockDim.x;
    for (int i = blockIdx.x * blockDim.x + threadIdx.x; i < n4; i += stride) {
        float4 x = r4[i];
        float4 y;
        y.x = fminf(fmaxf(x.x * scale, -CLIPR), CLIPR);
        y.y = fminf(fmaxf(x.y * scale, -CLIPR), CLIPR);
        y.z = fminf(fmaxf(x.z * scale, -CLIPR), CLIPR);
        y.w = fminf(fmaxf(x.w * scale, -CLIPR), CLIPR);
        o4[i] = y;
    }
}

extern "C" void kernel_launch(void* const* d_in, const int* in_sizes, int n_in,
                              void* d_out, int out_size, void* d_ws, size_t ws_size,
                              hipStream_t stream) {
    const float* rewards     = (const float*)d_in[0];
    const float* dones       = (const float*)d_in[1];
    const float* return_init = (const float*)d_in[2];
    const float* var_init    = (const float*)d_in[3];
    float* out = (float*)d_out;

    double* acc  = (double*)d_ws;
    float*  arrs = (float*)((char*)d_ws + 64);

    hipMemsetAsync(d_ws, 0, 16, stream);

    const size_t arrs128 = (size_t)7 * 128 * B * 4;
    const size_t arrs64  = (size_t)7 * 64  * B * 4;
    const size_t segsz   = (size_t)7 * GSEG * B * 4;

    const float2* r2 = (const float2*)rewards;
    const float2* d2 = (const float2*)dones;

    int C;
    float* segp = nullptr;
    if (ws_size >= 64 + arrs128) {
        C = 128;
        if (ws_size >= 64 + arrs128 + segsz) segp = (float*)((char*)d_ws + 64 + arrs128);
        dim3 g1((B / 2) / 256, C);
        chunk_scan_pipe<<<g1, 256, 0, stream>>>(r2, d2, arrs);
    } else {
        C = 64;
        if (ws_size >= 64 + arrs64 + segsz) segp = (float*)((char*)d_ws + 64 + arrs64);
        dim3 g1((B / 2) / 256, C);
        chunk_scan_simple<64><<<g1, 256, 0, stream>>>(r2, d2, arrs, C);
    }

    if (segp) {
        seg_compose<<<(B * GSEG) / 256, 256, 0, stream>>>(arrs, C, segp);
        carry_final<<<B / 256, 256, 0, stream>>>(segp, return_init, acc);
    } else {
        carry_reduce<<<B / 256, 256, 0, stream>>>(arrs, C, return_init, acc);
    }

    const int n4 = (T * B) / 4;
    normalize<<<4096, 256, 0, stream>>>(rewards, out, acc, var_init, n4);
}

// Round 6
// 62.787 us; speedup vs baseline: 1.0717x; 1.0507x over previous
//
#include <hip/hip_runtime.h>

#define GAMMA   0.99f
#define EPSILON 1e-8f
#define CLIPR   10.0f
#define VAR_MOM 0.99f

constexpr int T = 4096;
constexpr int B = 4096;
constexpr int GSEG = 16;

// ---------------------------------------------------------------------------
// K1 (row-burst mapping): block = 256 threads, each thread owns 4 adjacent
// columns (float4). Block x covers columns [x*1024,(x+1)*1024): per time-step
// the block reads a CONTIGUOUS 4 KB run of each row (wave = 1 KB contiguous).
// DRAM sees 4 KB sequential bursts instead of 512 B @ 16 KB stride (which
// measured at ~1.3 TB/s HBM). The t-recurrence stays serial per thread.
// ---------------------------------------------------------------------------
template <int L>
__global__ __launch_bounds__(256) void chunk_scan_rows(
    const float4* __restrict__ rewards,
    const float4* __restrict__ dones,
    float* __restrict__ arrs,   // 7 arrays, stride S=C*B
    int C) {
    constexpr int W4 = B / 4;                       // float4 per row
    const int q  = blockIdx.x * blockDim.x + threadIdx.x;  // [0, W4)
    const int c  = blockIdx.y;
    const int t0 = c * L;

    float v0 = 0.f, p0 = 1.f, sv0 = 0.f, sp0 = 0.f, sv20 = 0.f, svp0 = 0.f, sp20 = 0.f;
    float v1 = 0.f, p1 = 1.f, sv1 = 0.f, sp1 = 0.f, sv21 = 0.f, svp1 = 0.f, sp21 = 0.f;
    float v2 = 0.f, p2 = 1.f, sv2_ = 0.f, sp2_ = 0.f, sv22 = 0.f, svp2 = 0.f, sp22 = 0.f;
    float v3 = 0.f, p3 = 1.f, sv3 = 0.f, sp3 = 0.f, sv23 = 0.f, svp3 = 0.f, sp23 = 0.f;

#define UPD(vk, pk, svk, spk, sv2k, svpk, sp2k, rc, dc)                    \
    {                                                                      \
        const float a = GAMMA - GAMMA * (dc);                              \
        vk = fmaf(a, vk, (rc));  pk *= a;                                  \
        svk += vk;  spk += pk;                                             \
        sv2k = fmaf(vk, vk, sv2k);                                         \
        svpk = fmaf(vk, pk, svpk);                                         \
        sp2k = fmaf(pk, pk, sp2k);                                         \
    }

#pragma unroll 4
    for (int j = 0; j < L; ++j) {
        const int t = t0 + L - 1 - j;
        const float4 r = rewards[(size_t)t * W4 + q];
        const float4 d = dones  [(size_t)t * W4 + q];
        UPD(v0, p0, sv0, sp0, sv20, svp0, sp20, r.x, d.x)
        UPD(v1, p1, sv1, sp1, sv21, svp1, sp21, r.y, d.y)
        UPD(v2, p2, sv2_, sp2_, sv22, svp2, sp22, r.z, d.z)
        UPD(v3, p3, sv3, sp3, sv23, svp3, sp23, r.w, d.w)
    }
#undef UPD

    const size_t S   = (size_t)C * B;
    const size_t idx = (size_t)c * B + 4 * q;
    *(float4*)&arrs[0 * S + idx] = make_float4(v0,  v1,  v2,  v3);    // v_first
    *(float4*)&arrs[1 * S + idx] = make_float4(p0,  p1,  p2,  p3);    // p_tot
    *(float4*)&arrs[2 * S + idx] = make_float4(sv0, sv1, sv2_, sv3);
    *(float4*)&arrs[3 * S + idx] = make_float4(sp0, sp1, sp2_, sp3);
    *(float4*)&arrs[4 * S + idx] = make_float4(sv20, sv21, sv22, sv23);
    *(float4*)&arrs[5 * S + idx] = make_float4(svp0, svp1, svp2, svp3);
    *(float4*)&arrs[6 * S + idx] = make_float4(sp20, sp21, sp22, sp23);
}

// K2a: compose chunk summaries within each of GSEG segments per column.
__global__ void seg_compose(const float* __restrict__ arrs, int C,
                            float* __restrict__ seg) {
    const int tid = blockIdx.x * blockDim.x + threadIdx.x;
    const int b = tid & (B - 1);
    const int s = tid >> 12;
    const int Cs = C / GSEG;
    const size_t S = (size_t)C * B;
    float V = 0.f, P = 1.f, SV = 0.f, SP = 0.f, SV2 = 0.f, SVP = 0.f, SP2 = 0.f;
    for (int c = (s + 1) * Cs - 1; c >= s * Cs; --c) {
        const size_t idx = (size_t)c * B + b;
        const float vf  = arrs[0 * S + idx];
        const float pt  = arrs[1 * S + idx];
        const float sv  = arrs[2 * S + idx];
        const float sp  = arrs[3 * S + idx];
        const float sv2 = arrs[4 * S + idx];
        const float svp = arrs[5 * S + idx];
        const float sp2 = arrs[6 * S + idx];
        SV2 += sv2 + 2.f * svp * V + sp2 * V * V;
        SVP += svp * P + sp2 * V * P;
        SP2 += sp2 * P * P;
        SV  += sv + sp * V;
        SP  += sp * P;
        V = fmaf(pt, V, vf);
        P *= pt;
    }
    const size_t SG = (size_t)GSEG * B;
    const size_t o  = (size_t)s * B + b;
    seg[0 * SG + o] = V;   seg[1 * SG + o] = P;
    seg[2 * SG + o] = SV;  seg[3 * SG + o] = SP;
    seg[4 * SG + o] = SV2; seg[5 * SG + o] = SVP; seg[6 * SG + o] = SP2;
}

// K2b: finish carry across GSEG segments per column; exact sums in double.
__global__ void carry_final(const float* __restrict__ seg,
                            const float* __restrict__ return_init,
                            double* __restrict__ acc) {
    const int b = blockIdx.x * blockDim.x + threadIdx.x;
    const size_t SG = (size_t)GSEG * B;
    double s = 0.0, s2 = 0.0;
    float carry = return_init[0];
    for (int g = GSEG - 1; g >= 0; --g) {
        const size_t o = (size_t)g * B + b;
        const float V   = seg[0 * SG + o];
        const float P   = seg[1 * SG + o];
        const float SV  = seg[2 * SG + o];
        const float SP  = seg[3 * SG + o];
        const float SV2 = seg[4 * SG + o];
        const float SVP = seg[5 * SG + o];
        const float SP2 = seg[6 * SG + o];
        const double cd = (double)carry;
        s  += (double)SV  + cd * (double)SP;
        s2 += (double)SV2 + 2.0 * cd * (double)SVP + cd * cd * (double)SP2;
        carry = fmaf(P, carry, V);
    }
    __shared__ double sh_s[256];
    __shared__ double sh_s2[256];
    const int tid = threadIdx.x;
    sh_s[tid] = s; sh_s2[tid] = s2;
    __syncthreads();
    for (int stride = 128; stride > 0; stride >>= 1) {
        if (tid < stride) {
            sh_s[tid]  += sh_s[tid + stride];
            sh_s2[tid] += sh_s2[tid + stride];
        }
        __syncthreads();
    }
    if (tid == 0) {
        atomicAdd(&acc[0], sh_s[0]);
        atomicAdd(&acc[1], sh_s2[0]);
    }
}

// K2 fallback (single-level) if ws too small for seg scratch.
__global__ void carry_reduce(const float* __restrict__ arrs, int C,
                             const float* __restrict__ return_init,
                             double* __restrict__ acc) {
    const int b = blockIdx.x * blockDim.x + threadIdx.x;
    const size_t S = (size_t)C * B;
    double s = 0.0, s2 = 0.0;
    float carry = return_init[0];
#pragma unroll 4
    for (int c = C - 1; c >= 0; --c) {
        const size_t idx = (size_t)c * B + b;
        const float vf  = arrs[0 * S + idx];
        const float pt  = arrs[1 * S + idx];
        const float sv  = arrs[2 * S + idx];
        const float sp  = arrs[3 * S + idx];
        const float sv2 = arrs[4 * S + idx];
        const float svp = arrs[5 * S + idx];
        const float sp2 = arrs[6 * S + idx];
        const double cd = (double)carry;
        s  += (double)sv  + cd * (double)sp;
        s2 += (double)sv2 + 2.0 * cd * (double)svp + cd * cd * (double)sp2;
        carry = fmaf(pt, carry, vf);
    }
    __shared__ double sh_s[256];
    __shared__ double sh_s2[256];
    const int tid = threadIdx.x;
    sh_s[tid] = s; sh_s2[tid] = s2;
    __syncthreads();
    for (int stride = 128; stride > 0; stride >>= 1) {
        if (tid < stride) {
            sh_s[tid]  += sh_s[tid + stride];
            sh_s2[tid] += sh_s2[tid + stride];
        }
        __syncthreads();
    }
    if (tid == 0) {
        atomicAdd(&acc[0], sh_s[0]);
        atomicAdd(&acc[1], sh_s2[0]);
    }
}

// K3: scale = 1/sqrt(var_new + eps); out = clip(rewards * scale).
__global__ void normalize(const float* __restrict__ rewards,
                          float* __restrict__ out,
                          const double* __restrict__ acc,
                          const float* __restrict__ var_init,
                          int n4) {
    const double s  = acc[0];
    const double s2 = acc[1];
    const double n  = (double)T * (double)B;
    const double ret_var = (s2 - s * s / n) / (n - 1.0);
    const float var_new = (float)((double)var_init[0] * (double)VAR_MOM +
                                  ret_var * (1.0 - (double)VAR_MOM));
    const float scale = 1.0f / sqrtf(var_new + EPSILON);

    const float4* __restrict__ r4 = (const float4*)rewards;
    float4* __restrict__ o4 = (float4*)out;
    const int stride = gridDim.x * blockDim.x;
    for (int i = blockIdx.x * blockDim.x + threadIdx.x; i < n4; i += stride) {
        float4 x = r4[i];
        float4 y;
        y.x = fminf(fmaxf(x.x * scale, -CLIPR), CLIPR);
        y.y = fminf(fmaxf(x.y * scale, -CLIPR), CLIPR);
        y.z = fminf(fmaxf(x.z * scale, -CLIPR), CLIPR);
        y.w = fminf(fmaxf(x.w * scale, -CLIPR), CLIPR);
        o4[i] = y;
    }
}

extern "C" void kernel_launch(void* const* d_in, const int* in_sizes, int n_in,
                              void* d_out, int out_size, void* d_ws, size_t ws_size,
                              hipStream_t stream) {
    const float* rewards     = (const float*)d_in[0];
    const float* dones       = (const float*)d_in[1];
    const float* return_init = (const float*)d_in[2];
    const float* var_init    = (const float*)d_in[3];
    float* out = (float*)d_out;

    double* acc  = (double*)d_ws;
    float*  arrs = (float*)((char*)d_ws + 64);

    hipMemsetAsync(d_ws, 0, 16, stream);

    const size_t arrs128 = (size_t)7 * 128 * B * 4;
    const size_t arrs64  = (size_t)7 * 64  * B * 4;
    const size_t segsz   = (size_t)7 * GSEG * B * 4;

    const float4* r4 = (const float4*)rewards;
    const float4* d4 = (const float4*)dones;

    int C;
    float* segp = nullptr;
    if (ws_size >= 64 + arrs128) {
        C = 128;   // L=32; grid 4 x-slices x 128 chunks = 512 blocks, 16 waves/CU
        if (ws_size >= 64 + arrs128 + segsz) segp = (float*)((char*)d_ws + 64 + arrs128);
        dim3 g1((B / 4) / 256, C);
        chunk_scan_rows<32><<<g1, 256, 0, stream>>>(r4, d4, arrs, C);
    } else {
        C = 64;    // L=64
        if (ws_size >= 64 + arrs64 + segsz) segp = (float*)((char*)d_ws + 64 + arrs64);
        dim3 g1((B / 4) / 256, C);
        chunk_scan_rows<64><<<g1, 256, 0, stream>>>(r4, d4, arrs, C);
    }

    if (segp) {
        seg_compose<<<(B * GSEG) / 256, 256, 0, stream>>>(arrs, C, segp);
        carry_final<<<B / 256, 256, 0, stream>>>(segp, return_init, acc);
    } else {
        carry_reduce<<<B / 256, 256, 0, stream>>>(arrs, C, return_init, acc);
    }

    const int n4 = (T * B) / 4;
    normalize<<<4096, 256, 0, stream>>>(rewards, out, acc, var_init, n4);
}